// Round 2
// baseline (316.935 us; speedup 1.0000x reference)
//
#include <hip/hip_runtime.h>
#include <hip/hip_bf16.h>
#include <math.h>

// Problem constants
#define B_   32
#define N_   2248
#define C_   1024
#define D_   128
#define P_   200
#define T_   2048            // N_ - P_
#define M_   (B_ * N_)       // 71936 rows total
#define SCALE_ 0.08838834764831845f  // D^-0.5

typedef __bf16 bf16;
typedef __bf16 bf16x8 __attribute__((ext_vector_type(8)));
typedef __bf16 bf16x4 __attribute__((ext_vector_type(4)));
typedef float  f32x4  __attribute__((ext_vector_type(4)));
typedef unsigned int u32x4 __attribute__((ext_vector_type(4)));

// V-transpose LDS column swizzle (attn): keeps 8-contiguous t within a 16B
// block, XORs the 8-block index with (d>>3)&7 to spread banks.
#define VT_COL(dd, t) ((((((t) >> 3) ^ (((dd) >> 3) & 7)) << 3)) | ((t) & 7))

// ---------------------------------------------------------------------------
// Kernel 0: one-time weight transpose + bf16 convert.
// WtD[d][k] = W_down[k][d] (d<128, k<1024);  WtU[c][d] = W_up[d][c]
// ---------------------------------------------------------------------------
__global__ void k_prep(const float* __restrict__ Wd, const float* __restrict__ Wu,
                       bf16* __restrict__ WtD, bf16* __restrict__ WtU) {
    int i = blockIdx.x * 256 + threadIdx.x;
    if (i >= 131072) return;
    int d = i >> 10, k = i & 1023;
    WtD[i] = (bf16)Wd[k * 128 + d];
    int c = i >> 7, e = i & 127;
    WtU[i] = (bf16)Wu[e * 1024 + c];
}

// ---------------------------------------------------------------------------
// Kernel A: down = gelu(x @ W_down + b_down), bf16 out.
// DIRECT-FRAGMENT GEMM: no LDS, no barriers. Each lane loads its MFMA
// fragments straight from global (A: f32x8 + convert; B: contiguous bf16x8,
// L2-resident). Waves sharing rows hit L2 on the mirror read.
// 128x128 tile, 4 waves (2x2), 16x16x32 bf16 MFMA.
// ---------------------------------------------------------------------------
__launch_bounds__(256, 3)
__global__ void k_down(const float* __restrict__ x, const bf16* __restrict__ WtD,
                       const float* __restrict__ bd, bf16* __restrict__ down) {
    const int tid = threadIdx.x;
    const int lane = tid & 63, wid = tid >> 6;
    const int wm = wid >> 1, wn = wid & 1;
    const int li = lane & 15, lg = lane >> 4;
    const int m0 = blockIdx.x * 128;
    const float* Ap = x   + (size_t)(m0 + wm * 64 + li) * C_ + lg * 8;
    const bf16*  Bp = WtD + (size_t)(wn * 64 + li) * C_ + lg * 8;

    f32x4 acc[4][4];
    const f32x4 zero = {0.f, 0.f, 0.f, 0.f};
#pragma unroll
    for (int i = 0; i < 4; i++)
#pragma unroll
        for (int j = 0; j < 4; j++) acc[i][j] = zero;

    for (int k0 = 0; k0 < C_; k0 += 64) {
#pragma unroll
        for (int kk = 0; kk < 2; kk++) {
            bf16x8 af[4], bf_[4];
#pragma unroll
            for (int f = 0; f < 4; f++) {
                const float* s = Ap + (size_t)(f * 16) * C_ + k0 + kk * 32;
                f32x4 v0 = *(const f32x4*)s;
                f32x4 v1 = *(const f32x4*)(s + 4);
                bf16x8 o;
                o[0] = (bf16)v0[0]; o[1] = (bf16)v0[1]; o[2] = (bf16)v0[2]; o[3] = (bf16)v0[3];
                o[4] = (bf16)v1[0]; o[5] = (bf16)v1[1]; o[6] = (bf16)v1[2]; o[7] = (bf16)v1[3];
                af[f] = o;
                bf_[f] = *(const bf16x8*)(Bp + (size_t)(f * 16) * C_ + k0 + kk * 32);
            }
#pragma unroll
            for (int fm = 0; fm < 4; fm++)
#pragma unroll
                for (int fn = 0; fn < 4; fn++)
                    acc[fm][fn] = __builtin_amdgcn_mfma_f32_16x16x32_bf16(
                        af[fm], bf_[fn], acc[fm][fn], 0, 0, 0);
        }
    }
    // epilogue: bias + exact gelu, store bf16
#pragma unroll
    for (int fn = 0; fn < 4; fn++) {
        int col = wn * 64 + fn * 16 + li;
        float bias = bd[col];
#pragma unroll
        for (int fm = 0; fm < 4; fm++) {
            int rb = m0 + wm * 64 + fm * 16 + lg * 4;
#pragma unroll
            for (int r = 0; r < 4; r++) {
                float v = acc[fm][fn][r] + bias;
                float g = 0.5f * v * (1.0f + erff(v * 0.70710678118654752f));
                down[(size_t)(rb + r) * D_ + col] = (bf16)g;
            }
        }
    }
}

// ---------------------------------------------------------------------------
// Kernel B: flash attention, SPLIT over tokens (4 quarters of 512).
// grid = 32 b x 4 qtile x 4 thalf = 512 blocks (2/CU), XCD-swizzled.
// 4 waves; wave w owns q rows w*16..w*16+15. Token tiles of 64.
// Writes unnormalized partial O + running (m, l) per q row.
// ---------------------------------------------------------------------------
__launch_bounds__(256, 2)
__global__ void k_attn(const bf16* __restrict__ down, float* __restrict__ Opart,
                       float* __restrict__ Mpart, float* __restrict__ Lpart) {
    __shared__ bf16 Qs[64][136];
    __shared__ bf16 Ks[64][136];      // token tile row-major [t][d]
    __shared__ bf16 Vt[128][72];      // transposed [d][t], VT_COL swizzled
    __shared__ bf16 Ps[4][16][72];    // per-wave P tile [q][t]
    const int tid = threadIdx.x;
    const int lane = tid & 63, w = tid >> 6;
    const int li = lane & 15, lg = lane >> 4;
    // bijective XCD swizzle (512 % 8 == 0): XCD x gets 64 contiguous wgs
    const int bid = blockIdx.x;
    const int wg = (bid & 7) * 64 + (bid >> 3);
    const int b  = wg >> 4;
    const int qt = (wg >> 2) & 3;
    const int th = wg & 3;
    const size_t base = (size_t)b * N_ * D_;
    const int tbase = P_ + th * 512;

    // stage Q (rows qt*64 .. +63)
#pragma unroll
    for (int it = 0; it < 4; it++) {
        int ch = tid + it * 256;            // 1024 chunks of 8
        int r = ch >> 4, c8 = (ch & 15) * 8;
        *(u32x4*)&Qs[r][c8] = *(const u32x4*)(down + base + (size_t)(qt * 64 + r) * D_ + c8);
    }
    __syncthreads();
    bf16x8 qf[4];
#pragma unroll
    for (int kk = 0; kk < 4; kk++)
        qf[kk] = *(const bf16x8*)&Qs[w * 16 + li][kk * 32 + lg * 8];

    float m_run[4], l_run[4];
    f32x4 acc[8];
    const f32x4 zero = {0.f, 0.f, 0.f, 0.f};
#pragma unroll
    for (int r = 0; r < 4; r++) { m_run[r] = -3.0e38f; l_run[r] = 0.f; }
#pragma unroll
    for (int fn = 0; fn < 8; fn++) acc[fn] = zero;

    for (int tt = 0; tt < 8; tt++) {
        __syncthreads();
        // stage token tile: row-major K copy + swizzled transposed V copy
#pragma unroll
        for (int it = 0; it < 4; it++) {
            int ch = tid + it * 256;
            int r = ch >> 4, c8 = (ch & 15) * 8;
            u32x4 v = *(const u32x4*)(down + base + (size_t)(tbase + tt * 64 + r) * D_ + c8);
            *(u32x4*)&Ks[r][c8] = v;
            bf16 tmp[8];
            *(u32x4*)tmp = v;
#pragma unroll
            for (int j = 0; j < 8; j++) Vt[c8 + j][VT_COL(c8 + j, r)] = tmp[j];
        }
        __syncthreads();
        // S = Q K^T * scale   (wave: 16 q x 64 t)
        f32x4 s[4];
#pragma unroll
        for (int fn = 0; fn < 4; fn++) {
            s[fn] = zero;
#pragma unroll
            for (int kk = 0; kk < 4; kk++) {
                bf16x8 kf = *(const bf16x8*)&Ks[fn * 16 + li][kk * 32 + lg * 8];
                s[fn] = __builtin_amdgcn_mfma_f32_16x16x32_bf16(qf[kk], kf, s[fn], 0, 0, 0);
            }
            s[fn] *= SCALE_;
        }
        // online softmax (rows shared by 16-lane group; reduce over li)
#pragma unroll
        for (int r = 0; r < 4; r++) {
            float tmax = fmaxf(fmaxf(s[0][r], s[1][r]), fmaxf(s[2][r], s[3][r]));
#pragma unroll
            for (int off = 1; off < 16; off <<= 1)
                tmax = fmaxf(tmax, __shfl_xor(tmax, off, 64));
            float mnew = fmaxf(m_run[r], tmax);
            float corr = __expf(m_run[r] - mnew);
            m_run[r] = mnew;
            float psum = 0.f;
#pragma unroll
            for (int fn = 0; fn < 4; fn++) {
                float p = __expf(s[fn][r] - mnew);
                psum += p;
                Ps[w][lg * 4 + r][fn * 16 + li] = (bf16)p;
            }
#pragma unroll
            for (int off = 1; off < 16; off <<= 1)
                psum += __shfl_xor(psum, off, 64);
            l_run[r] = l_run[r] * corr + psum;
#pragma unroll
            for (int fn = 0; fn < 8; fn++) acc[fn][r] *= corr;
        }
        // O += P V   (P: 16x64 per wave, V: 64x128)
#pragma unroll
        for (int kk = 0; kk < 2; kk++) {
            bf16x8 pf = *(const bf16x8*)&Ps[w][li][kk * 32 + lg * 8];
#pragma unroll
            for (int fn = 0; fn < 8; fn++) {
                int d = fn * 16 + li;
                bf16x8 vf = *(const bf16x8*)&Vt[d][VT_COL(d, kk * 32 + lg * 8)];
                acc[fn] = __builtin_amdgcn_mfma_f32_16x16x32_bf16(pf, vf, acc[fn], 0, 0, 0);
            }
        }
    }
    // epilogue: store unnormalized partials + (m, l) for all 64 q rows
#pragma unroll
    for (int r = 0; r < 4; r++) {
        int q = qt * 64 + w * 16 + lg * 4 + r;
        size_t ro = ((size_t)(b * 4 + th) * 256 + q) * 128;
#pragma unroll
        for (int fn = 0; fn < 8; fn++)
            Opart[ro + fn * 16 + li] = acc[fn][r];
        if (li == 0) {
            Mpart[(b * 4 + th) * 256 + q] = m_run[r];
            Lpart[(b * 4 + th) * 256 + q] = l_run[r];
        }
    }
}

// ---------------------------------------------------------------------------
// Kernel B2: combine the four token-quarter partials into pout (bf16).
// 819200 elems / 4 per thread = 204800 threads = 800 blocks x 256.
// ---------------------------------------------------------------------------
__global__ void k_comb(const float* __restrict__ Opart, const float* __restrict__ Mpart,
                       const float* __restrict__ Lpart, bf16* __restrict__ pout) {
    int gid = blockIdx.x * 256 + threadIdx.x;
    if (gid >= (B_ * P_ * D_) / 4) return;
    int e = gid * 4;
    int row = e >> 7;                 // 0..6399  (b*200+q)
    int col = e & 127;
    int b = row / P_;
    int q = row - b * P_;
    float mm[4], ll[4];
    float m = -3.0e38f;
#pragma unroll
    for (int t = 0; t < 4; t++) {
        mm[t] = Mpart[(b * 4 + t) * 256 + q];
        ll[t] = Lpart[(b * 4 + t) * 256 + q];
        m = fmaxf(m, mm[t]);
    }
    float a[4], lsum = 0.f;
#pragma unroll
    for (int t = 0; t < 4; t++) { a[t] = __expf(mm[t] - m); lsum += ll[t] * a[t]; }
    float inv = 1.0f / lsum;
    f32x4 o = {0.f, 0.f, 0.f, 0.f};
#pragma unroll
    for (int t = 0; t < 4; t++) {
        f32x4 ot = *(const f32x4*)&Opart[((size_t)(b * 4 + t) * 256 + q) * 128 + col];
#pragma unroll
        for (int j = 0; j < 4; j++) o[j] += ot[j] * a[t];
    }
    bf16x4 ob;
#pragma unroll
    for (int j = 0; j < 4; j++) ob[j] = (bf16)(o[j] * inv);
    *(bf16x4*)&pout[(size_t)row * 128 + col] = ob;
}

// ---------------------------------------------------------------------------
// Kernel C: out = gate * (combined @ W_up + b_up).  K=128 single shot.
// DIRECT-FRAGMENT GEMM: no LDS, no barriers. Per-lane row pointers select
// pout (n<200) vs down once; fragments are contiguous 16B loads (L2-hot).
// 128x128 tile, 4 waves (2x2). XCD-aware block swizzle (4496 % 8 == 0).
// ---------------------------------------------------------------------------
__launch_bounds__(256, 3)
__global__ void k_up(const bf16* __restrict__ down, const bf16* __restrict__ pout,
                     const bf16* __restrict__ WtU, const float* __restrict__ bu,
                     const float* __restrict__ gate, float* __restrict__ out) {
    const int tid = threadIdx.x;
    const int lane = tid & 63, wid = tid >> 6;
    const int wm = wid >> 1, wn = wid & 1;
    const int li = lane & 15, lg = lane >> 4;
    // bijective XCD swizzle: XCD x gets contiguous wg range [562x, 562x+562)
    int bid = blockIdx.x;
    int wg = (bid & 7) * 562 + (bid >> 3);
    const int mt = wg >> 3, nt = wg & 7;
    const int m0 = mt * 128, n0 = nt * 128;

    // per-lane A row pointers (combined matrix), one per fm fragment
    const bf16* rp[4];
#pragma unroll
    for (int f = 0; f < 4; f++) {
        int row = m0 + wm * 64 + f * 16 + li;
        int bb = row / N_;
        int n = row - bb * N_;
        rp[f] = (n < P_) ? (pout + (size_t)(bb * P_ + n) * D_ + lg * 8)
                         : (down + (size_t)row * D_ + lg * 8);
    }
    const bf16* Bp = WtU + (size_t)(n0 + wn * 64 + li) * D_ + lg * 8;

    f32x4 acc[4][4];
    const f32x4 zero = {0.f, 0.f, 0.f, 0.f};
#pragma unroll
    for (int i = 0; i < 4; i++)
#pragma unroll
        for (int j = 0; j < 4; j++) acc[i][j] = zero;

#pragma unroll
    for (int kk = 0; kk < 4; kk++) {
        bf16x8 af[4], bf_[4];
#pragma unroll
        for (int f = 0; f < 4; f++) {
            af[f]  = *(const bf16x8*)(rp[f] + kk * 32);
            bf_[f] = *(const bf16x8*)(Bp + (size_t)(f * 16) * D_ + kk * 32);
        }
#pragma unroll
        for (int fm = 0; fm < 4; fm++)
#pragma unroll
            for (int fn = 0; fn < 4; fn++)
                acc[fm][fn] = __builtin_amdgcn_mfma_f32_16x16x32_bf16(
                    af[fm], bf_[fn], acc[fm][fn], 0, 0, 0);
    }

    float g = gate[0];
#pragma unroll
    for (int fn = 0; fn < 4; fn++) {
        int c = n0 + wn * 64 + fn * 16 + li;
        float bias = bu[c];
#pragma unroll
        for (int fm = 0; fm < 4; fm++) {
            int rb = m0 + wm * 64 + fm * 16 + lg * 4;
#pragma unroll
            for (int r = 0; r < 4; r++)
                out[(size_t)(rb + r) * C_ + c] = g * (acc[fm][fn][r] + bias);
        }
    }
}

// ---------------------------------------------------------------------------
extern "C" void kernel_launch(void* const* d_in, const int* in_sizes, int n_in,
                              void* d_out, int out_size, void* d_ws, size_t ws_size,
                              hipStream_t stream) {
    const float* x    = (const float*)d_in[0];
    const float* Wd   = (const float*)d_in[1];
    const float* bd   = (const float*)d_in[2];
    const float* Wu   = (const float*)d_in[3];
    const float* bu   = (const float*)d_in[4];
    const float* gate = (const float*)d_in[5];
    float* out = (float*)d_out;

    char* w = (char*)d_ws;
    bf16*  down  = (bf16*)w;                          // 71936*128*2 = 18,415,616 B
    bf16*  pout  = (bf16*)(w + 18415616);             // 32*200*128*2 = 1,638,400 B
    bf16*  WtD   = (bf16*)(w + 20054016);             // 262,144 B
    bf16*  WtU   = (bf16*)(w + 20316160);             // 262,144 B
    float* Opart = (float*)(w + 20578304);            // 32*4*256*128*4 = 16,777,216 B
    float* Mpart = (float*)(w + 37355520);            // 131,072 B
    float* Lpart = (float*)(w + 37486592);            // 131,072 B  (total 37.6 MB)

    k_prep<<<512, 256, 0, stream>>>(Wd, Wu, WtD, WtU);
    k_down<<<M_ / 128, 256, 0, stream>>>(x, WtD, bd, down);            // 562 blocks
    k_attn<<<512, 256, 0, stream>>>(down, Opart, Mpart, Lpart);        // 512 blocks
    k_comb<<<800, 256, 0, stream>>>(Opart, Mpart, Lpart, pout);        // 800 blocks
    k_up<<<(M_ / 128) * 8, 256, 0, stream>>>(down, pout, WtU, bu, gate, out); // 4496
}

// Round 3
// 255.730 us; speedup vs baseline: 1.2393x; 1.2393x over previous
//
#include <hip/hip_runtime.h>
#include <hip/hip_bf16.h>
#include <math.h>

// Problem constants
#define B_   32
#define N_   2248
#define C_   1024
#define D_   128
#define P_   200
#define T_   2048            // N_ - P_
#define M_   (B_ * N_)       // 71936 rows total
#define SCALE_ 0.08838834764831845f  // D^-0.5

typedef __bf16 bf16;
typedef __bf16 bf16x8 __attribute__((ext_vector_type(8)));
typedef __bf16 bf16x4 __attribute__((ext_vector_type(4)));
typedef float  f32x4  __attribute__((ext_vector_type(4)));
typedef unsigned int u32x4 __attribute__((ext_vector_type(4)));

// V-transpose LDS column swizzle (attn): keeps 8-contiguous t within a 16B
// block, XORs the 8-block index with (d>>3)&7 to spread banks.
#define VT_COL(dd, t) ((((((t) >> 3) ^ (((dd) >> 3) & 7)) << 3)) | ((t) & 7))

// ---------------------------------------------------------------------------
// Kernel 0: one-time weight transpose + bf16 convert.
// WtD[d][k] = W_down[k][d] (d<128, k<1024);  WtU[c][d] = W_up[d][c]
// ---------------------------------------------------------------------------
__global__ void k_prep(const float* __restrict__ Wd, const float* __restrict__ Wu,
                       bf16* __restrict__ WtD, bf16* __restrict__ WtU) {
    int i = blockIdx.x * 256 + threadIdx.x;
    if (i >= 131072) return;
    int d = i >> 10, k = i & 1023;
    WtD[i] = (bf16)Wd[k * 128 + d];
    int c = i >> 7, e = i & 127;
    WtU[i] = (bf16)Wu[e * 1024 + c];
}

// ---------------------------------------------------------------------------
// Kernel A: down = gelu(x @ W_down + b_down), bf16 out.
// LDS-staged A (f32 -> bf16 convert) with T14 async double-buffer:
//   per k-step: barrier; issue NEXT tile's global loads to regs;
//   compute CURRENT tile from LDS (B fragments direct from L2-resident WtD);
//   convert+write regs -> alternate LDS buffer.
// One barrier per k-step; HBM latency hides under the 16 MFMAs.
// 128x128 tile, BK=64, 4 waves (2x2), 16x16x32 bf16 MFMA.
// ---------------------------------------------------------------------------
__launch_bounds__(256, 3)
__global__ void k_down(const float* __restrict__ x, const bf16* __restrict__ WtD,
                       const float* __restrict__ bd, bf16* __restrict__ down) {
    __shared__ bf16 As[2][128][72];   // double-buffered x tile (pad: 144B stride)
    const int tid = threadIdx.x;
    const int lane = tid & 63, wid = tid >> 6;
    const int wm = wid >> 1, wn = wid & 1;
    const int li = lane & 15, lg = lane >> 4;
    const int m0 = blockIdx.x * 128;
    const bf16* Bp = WtD + (size_t)(wn * 64 + li) * C_ + lg * 8;

    // per-thread staging coordinates: 4 chunks of 8 floats (1024 chunks total)
    int r_[4], c_[4];
    const float* sp[4];
#pragma unroll
    for (int it = 0; it < 4; it++) {
        int ch = tid + it * 256;
        r_[it] = ch >> 3;
        c_[it] = (ch & 7) * 8;
        sp[it] = x + (size_t)(m0 + r_[it]) * C_ + c_[it];
    }

    f32x4 stg[8];
    // prologue: load k-tile 0 and write buffer 0
#pragma unroll
    for (int it = 0; it < 4; it++) {
        stg[2 * it]     = *(const f32x4*)(sp[it]);
        stg[2 * it + 1] = *(const f32x4*)(sp[it] + 4);
    }
#pragma unroll
    for (int it = 0; it < 4; it++) {
        bf16x8 o;
        o[0] = (bf16)stg[2*it][0]; o[1] = (bf16)stg[2*it][1];
        o[2] = (bf16)stg[2*it][2]; o[3] = (bf16)stg[2*it][3];
        o[4] = (bf16)stg[2*it+1][0]; o[5] = (bf16)stg[2*it+1][1];
        o[6] = (bf16)stg[2*it+1][2]; o[7] = (bf16)stg[2*it+1][3];
        *(bf16x8*)&As[0][r_[it]][c_[it]] = o;
    }

    f32x4 acc[4][4];
    const f32x4 zero = {0.f, 0.f, 0.f, 0.f};
#pragma unroll
    for (int i = 0; i < 4; i++)
#pragma unroll
        for (int j = 0; j < 4; j++) acc[i][j] = zero;

    int cur = 0;
    for (int t = 0; t < 16; t++) {
        __syncthreads();                    // buf[cur] fully written
        if (t < 15) {
            // issue next tile's loads NOW; they complete under the MFMAs below
#pragma unroll
            for (int it = 0; it < 4; it++) {
                stg[2 * it]     = *(const f32x4*)(sp[it] + (t + 1) * 64);
                stg[2 * it + 1] = *(const f32x4*)(sp[it] + (t + 1) * 64 + 4);
            }
        }
        const int k0 = t * 64;
#pragma unroll
        for (int kk = 0; kk < 2; kk++) {
            bf16x8 af[4], bf_[4];
#pragma unroll
            for (int f = 0; f < 4; f++)
                bf_[f] = *(const bf16x8*)(Bp + (size_t)(f * 16) * C_ + k0 + kk * 32);
#pragma unroll
            for (int f = 0; f < 4; f++)
                af[f] = *(const bf16x8*)&As[cur][wm * 64 + f * 16 + li][kk * 32 + lg * 8];
#pragma unroll
            for (int fm = 0; fm < 4; fm++)
#pragma unroll
                for (int fn = 0; fn < 4; fn++)
                    acc[fm][fn] = __builtin_amdgcn_mfma_f32_16x16x32_bf16(
                        af[fm], bf_[fn], acc[fm][fn], 0, 0, 0);
        }
        if (t < 15) {
            // convert + write into the buffer nobody reads until next barrier
#pragma unroll
            for (int it = 0; it < 4; it++) {
                bf16x8 o;
                o[0] = (bf16)stg[2*it][0]; o[1] = (bf16)stg[2*it][1];
                o[2] = (bf16)stg[2*it][2]; o[3] = (bf16)stg[2*it][3];
                o[4] = (bf16)stg[2*it+1][0]; o[5] = (bf16)stg[2*it+1][1];
                o[6] = (bf16)stg[2*it+1][2]; o[7] = (bf16)stg[2*it+1][3];
                *(bf16x8*)&As[cur ^ 1][r_[it]][c_[it]] = o;
            }
        }
        cur ^= 1;
    }
    // epilogue: bias + exact gelu, store bf16
#pragma unroll
    for (int fn = 0; fn < 4; fn++) {
        int col = wn * 64 + fn * 16 + li;
        float bias = bd[col];
#pragma unroll
        for (int fm = 0; fm < 4; fm++) {
            int rb = m0 + wm * 64 + fm * 16 + lg * 4;
#pragma unroll
            for (int r = 0; r < 4; r++) {
                float v = acc[fm][fn][r] + bias;
                float g = 0.5f * v * (1.0f + erff(v * 0.70710678118654752f));
                down[(size_t)(rb + r) * D_ + col] = (bf16)g;
            }
        }
    }
}

// ---------------------------------------------------------------------------
// Kernel B: flash attention, SPLIT over tokens (4 quarters of 512).
// grid = 32 b x 4 qtile x 4 thalf = 512 blocks (2/CU), XCD-swizzled.
// 4 waves; wave w owns q rows w*16..w*16+15. Token tiles of 64.
// Writes unnormalized partial O + running (m, l) per q row.
// ---------------------------------------------------------------------------
__launch_bounds__(256, 2)
__global__ void k_attn(const bf16* __restrict__ down, float* __restrict__ Opart,
                       float* __restrict__ Mpart, float* __restrict__ Lpart) {
    __shared__ bf16 Qs[64][136];
    __shared__ bf16 Ks[64][136];      // token tile row-major [t][d]
    __shared__ bf16 Vt[128][72];      // transposed [d][t], VT_COL swizzled
    __shared__ bf16 Ps[4][16][72];    // per-wave P tile [q][t]
    const int tid = threadIdx.x;
    const int lane = tid & 63, w = tid >> 6;
    const int li = lane & 15, lg = lane >> 4;
    // bijective XCD swizzle (512 % 8 == 0): XCD x gets 64 contiguous wgs
    const int bid = blockIdx.x;
    const int wg = (bid & 7) * 64 + (bid >> 3);
    const int b  = wg >> 4;
    const int qt = (wg >> 2) & 3;
    const int th = wg & 3;
    const size_t base = (size_t)b * N_ * D_;
    const int tbase = P_ + th * 512;

    // stage Q (rows qt*64 .. +63)
#pragma unroll
    for (int it = 0; it < 4; it++) {
        int ch = tid + it * 256;            // 1024 chunks of 8
        int r = ch >> 4, c8 = (ch & 15) * 8;
        *(u32x4*)&Qs[r][c8] = *(const u32x4*)(down + base + (size_t)(qt * 64 + r) * D_ + c8);
    }
    __syncthreads();
    bf16x8 qf[4];
#pragma unroll
    for (int kk = 0; kk < 4; kk++)
        qf[kk] = *(const bf16x8*)&Qs[w * 16 + li][kk * 32 + lg * 8];

    float m_run[4], l_run[4];
    f32x4 acc[8];
    const f32x4 zero = {0.f, 0.f, 0.f, 0.f};
#pragma unroll
    for (int r = 0; r < 4; r++) { m_run[r] = -3.0e38f; l_run[r] = 0.f; }
#pragma unroll
    for (int fn = 0; fn < 8; fn++) acc[fn] = zero;

    for (int tt = 0; tt < 8; tt++) {
        __syncthreads();
        // stage token tile: row-major K copy + swizzled transposed V copy
#pragma unroll
        for (int it = 0; it < 4; it++) {
            int ch = tid + it * 256;
            int r = ch >> 4, c8 = (ch & 15) * 8;
            u32x4 v = *(const u32x4*)(down + base + (size_t)(tbase + tt * 64 + r) * D_ + c8);
            *(u32x4*)&Ks[r][c8] = v;
            bf16 tmp[8];
            *(u32x4*)tmp = v;
#pragma unroll
            for (int j = 0; j < 8; j++) Vt[c8 + j][VT_COL(c8 + j, r)] = tmp[j];
        }
        __syncthreads();
        // S = Q K^T * scale   (wave: 16 q x 64 t)
        f32x4 s[4];
#pragma unroll
        for (int fn = 0; fn < 4; fn++) {
            s[fn] = zero;
#pragma unroll
            for (int kk = 0; kk < 4; kk++) {
                bf16x8 kf = *(const bf16x8*)&Ks[fn * 16 + li][kk * 32 + lg * 8];
                s[fn] = __builtin_amdgcn_mfma_f32_16x16x32_bf16(qf[kk], kf, s[fn], 0, 0, 0);
            }
            s[fn] *= SCALE_;
        }
        // online softmax (rows shared by 16-lane group; reduce over li)
#pragma unroll
        for (int r = 0; r < 4; r++) {
            float tmax = fmaxf(fmaxf(s[0][r], s[1][r]), fmaxf(s[2][r], s[3][r]));
#pragma unroll
            for (int off = 1; off < 16; off <<= 1)
                tmax = fmaxf(tmax, __shfl_xor(tmax, off, 64));
            float mnew = fmaxf(m_run[r], tmax);
            float corr = __expf(m_run[r] - mnew);
            m_run[r] = mnew;
            float psum = 0.f;
#pragma unroll
            for (int fn = 0; fn < 4; fn++) {
                float p = __expf(s[fn][r] - mnew);
                psum += p;
                Ps[w][lg * 4 + r][fn * 16 + li] = (bf16)p;
            }
#pragma unroll
            for (int off = 1; off < 16; off <<= 1)
                psum += __shfl_xor(psum, off, 64);
            l_run[r] = l_run[r] * corr + psum;
#pragma unroll
            for (int fn = 0; fn < 8; fn++) acc[fn][r] *= corr;
        }
        // O += P V   (P: 16x64 per wave, V: 64x128)
#pragma unroll
        for (int kk = 0; kk < 2; kk++) {
            bf16x8 pf = *(const bf16x8*)&Ps[w][li][kk * 32 + lg * 8];
#pragma unroll
            for (int fn = 0; fn < 8; fn++) {
                int d = fn * 16 + li;
                bf16x8 vf = *(const bf16x8*)&Vt[d][VT_COL(d, kk * 32 + lg * 8)];
                acc[fn] = __builtin_amdgcn_mfma_f32_16x16x32_bf16(pf, vf, acc[fn], 0, 0, 0);
            }
        }
    }
    // epilogue: store unnormalized partials + (m, l) for all 64 q rows
#pragma unroll
    for (int r = 0; r < 4; r++) {
        int q = qt * 64 + w * 16 + lg * 4 + r;
        size_t ro = ((size_t)(b * 4 + th) * 256 + q) * 128;
#pragma unroll
        for (int fn = 0; fn < 8; fn++)
            Opart[ro + fn * 16 + li] = acc[fn][r];
        if (li == 0) {
            Mpart[(b * 4 + th) * 256 + q] = m_run[r];
            Lpart[(b * 4 + th) * 256 + q] = l_run[r];
        }
    }
}

// ---------------------------------------------------------------------------
// Kernel B2: combine the four token-quarter partials into pout (bf16).
// 819200 elems / 4 per thread = 204800 threads = 800 blocks x 256.
// ---------------------------------------------------------------------------
__global__ void k_comb(const float* __restrict__ Opart, const float* __restrict__ Mpart,
                       const float* __restrict__ Lpart, bf16* __restrict__ pout) {
    int gid = blockIdx.x * 256 + threadIdx.x;
    if (gid >= (B_ * P_ * D_) / 4) return;
    int e = gid * 4;
    int row = e >> 7;                 // 0..6399  (b*200+q)
    int col = e & 127;
    int b = row / P_;
    int q = row - b * P_;
    float mm[4], ll[4];
    float m = -3.0e38f;
#pragma unroll
    for (int t = 0; t < 4; t++) {
        mm[t] = Mpart[(b * 4 + t) * 256 + q];
        ll[t] = Lpart[(b * 4 + t) * 256 + q];
        m = fmaxf(m, mm[t]);
    }
    float a[4], lsum = 0.f;
#pragma unroll
    for (int t = 0; t < 4; t++) { a[t] = __expf(mm[t] - m); lsum += ll[t] * a[t]; }
    float inv = 1.0f / lsum;
    f32x4 o = {0.f, 0.f, 0.f, 0.f};
#pragma unroll
    for (int t = 0; t < 4; t++) {
        f32x4 ot = *(const f32x4*)&Opart[((size_t)(b * 4 + t) * 256 + q) * 128 + col];
#pragma unroll
        for (int j = 0; j < 4; j++) o[j] += ot[j] * a[t];
    }
    bf16x4 ob;
#pragma unroll
    for (int j = 0; j < 4; j++) ob[j] = (bf16)(o[j] * inv);
    *(bf16x4*)&pout[(size_t)row * 128 + col] = ob;
}

// ---------------------------------------------------------------------------
// Kernel C: out = gate * (combined @ W_up + b_up).  K=128 single shot.
// DIRECT-FRAGMENT GEMM: no LDS, no barriers. All loads issue up front
// (single K block -> no dependent per-iteration chain, unlike k_down).
// 128x128 tile, 4 waves (2x2). XCD-aware block swizzle (4496 % 8 == 0).
// ---------------------------------------------------------------------------
__launch_bounds__(256, 3)
__global__ void k_up(const bf16* __restrict__ down, const bf16* __restrict__ pout,
                     const bf16* __restrict__ WtU, const float* __restrict__ bu,
                     const float* __restrict__ gate, float* __restrict__ out) {
    const int tid = threadIdx.x;
    const int lane = tid & 63, wid = tid >> 6;
    const int wm = wid >> 1, wn = wid & 1;
    const int li = lane & 15, lg = lane >> 4;
    // bijective XCD swizzle: XCD x gets contiguous wg range [562x, 562x+562)
    int bid = blockIdx.x;
    int wg = (bid & 7) * 562 + (bid >> 3);
    const int mt = wg >> 3, nt = wg & 7;
    const int m0 = mt * 128, n0 = nt * 128;

    // per-lane A row pointers (combined matrix), one per fm fragment
    const bf16* rp[4];
#pragma unroll
    for (int f = 0; f < 4; f++) {
        int row = m0 + wm * 64 + f * 16 + li;
        int bb = row / N_;
        int n = row - bb * N_;
        rp[f] = (n < P_) ? (pout + (size_t)(bb * P_ + n) * D_ + lg * 8)
                         : (down + (size_t)row * D_ + lg * 8);
    }
    const bf16* Bp = WtU + (size_t)(n0 + wn * 64 + li) * D_ + lg * 8;

    f32x4 acc[4][4];
    const f32x4 zero = {0.f, 0.f, 0.f, 0.f};
#pragma unroll
    for (int i = 0; i < 4; i++)
#pragma unroll
        for (int j = 0; j < 4; j++) acc[i][j] = zero;

#pragma unroll
    for (int kk = 0; kk < 4; kk++) {
        bf16x8 af[4], bf_[4];
#pragma unroll
        for (int f = 0; f < 4; f++) {
            af[f]  = *(const bf16x8*)(rp[f] + kk * 32);
            bf_[f] = *(const bf16x8*)(Bp + (size_t)(f * 16) * D_ + kk * 32);
        }
#pragma unroll
        for (int fm = 0; fm < 4; fm++)
#pragma unroll
            for (int fn = 0; fn < 4; fn++)
                acc[fm][fn] = __builtin_amdgcn_mfma_f32_16x16x32_bf16(
                    af[fm], bf_[fn], acc[fm][fn], 0, 0, 0);
    }

    float g = gate[0];
#pragma unroll
    for (int fn = 0; fn < 4; fn++) {
        int c = n0 + wn * 64 + fn * 16 + li;
        float bias = bu[c];
#pragma unroll
        for (int fm = 0; fm < 4; fm++) {
            int rb = m0 + wm * 64 + fm * 16 + lg * 4;
#pragma unroll
            for (int r = 0; r < 4; r++)
                out[(size_t)(rb + r) * C_ + c] = g * (acc[fm][fn][r] + bias);
        }
    }
}

// ---------------------------------------------------------------------------
extern "C" void kernel_launch(void* const* d_in, const int* in_sizes, int n_in,
                              void* d_out, int out_size, void* d_ws, size_t ws_size,
                              hipStream_t stream) {
    const float* x    = (const float*)d_in[0];
    const float* Wd   = (const float*)d_in[1];
    const float* bd   = (const float*)d_in[2];
    const float* Wu   = (const float*)d_in[3];
    const float* bu   = (const float*)d_in[4];
    const float* gate = (const float*)d_in[5];
    float* out = (float*)d_out;

    char* w = (char*)d_ws;
    bf16*  down  = (bf16*)w;                          // 71936*128*2 = 18,415,616 B
    bf16*  pout  = (bf16*)(w + 18415616);             // 32*200*128*2 = 1,638,400 B
    bf16*  WtD   = (bf16*)(w + 20054016);             // 262,144 B
    bf16*  WtU   = (bf16*)(w + 20316160);             // 262,144 B
    float* Opart = (float*)(w + 20578304);            // 32*4*256*128*4 = 16,777,216 B
    float* Mpart = (float*)(w + 37355520);            // 131,072 B
    float* Lpart = (float*)(w + 37486592);            // 131,072 B  (total 37.6 MB)

    k_prep<<<512, 256, 0, stream>>>(Wd, Wu, WtD, WtU);
    k_down<<<M_ / 128, 256, 0, stream>>>(x, WtD, bd, down);            // 562 blocks
    k_attn<<<512, 256, 0, stream>>>(down, Opart, Mpart, Lpart);        // 512 blocks
    k_comb<<<800, 256, 0, stream>>>(Opart, Mpart, Lpart, pout);        // 800 blocks
    k_up<<<(M_ / 128) * 8, 256, 0, stream>>>(down, pout, WtU, bu, gate, out); // 4496
}